// Round 1
// baseline (3707.584 us; speedup 1.0000x reference)
//
#include <hip/hip_runtime.h>
#include <math.h>

#define HID 128
#define NB 32   // nodes per block in fused layer kernel

// ---------- CSR build ----------
__global__ void degree_k(const int* __restrict__ col, int* __restrict__ counts, int E) {
    int e = blockIdx.x * 256 + threadIdx.x;
    if (e < E) atomicAdd(&counts[col[e]], 1);
}

__global__ void dinv_k(const int* __restrict__ counts, float* __restrict__ dinv, int N) {
    int i = blockIdx.x * 256 + threadIdx.x;
    if (i < N) dinv[i] = rsqrtf((float)counts[i] + 1.0f);
}

__global__ void scan1_k(const int* __restrict__ counts, int* __restrict__ row_ptr,
                        int* __restrict__ blocksums, int N) {
    __shared__ int tmp[256];
    int t = threadIdx.x;
    int i = blockIdx.x * 256 + t;
    int v = (i < N) ? counts[i] : 0;
    tmp[t] = v;
    __syncthreads();
    for (int off = 1; off < 256; off <<= 1) {
        int x = (t >= off) ? tmp[t - off] : 0;
        __syncthreads();
        tmp[t] += x;
        __syncthreads();
    }
    if (i < N) row_ptr[i] = tmp[t] - v;          // exclusive within block
    if (t == 255) blocksums[blockIdx.x] = tmp[t]; // block total
}

__global__ void scan2_k(const int* __restrict__ blocksums, int* __restrict__ blockoffs, int nb) {
    __shared__ int tmp[512];
    int t = threadIdx.x;
    int v = (t < nb) ? blocksums[t] : 0;
    tmp[t] = v;
    __syncthreads();
    for (int off = 1; off < 512; off <<= 1) {
        int x = (t >= off) ? tmp[t - off] : 0;
        __syncthreads();
        tmp[t] += x;
        __syncthreads();
    }
    if (t < nb) blockoffs[t] = tmp[t] - v;        // exclusive
}

__global__ void scan3_k(int* __restrict__ row_ptr, const int* __restrict__ blockoffs, int N, int E) {
    int i = blockIdx.x * 256 + threadIdx.x;
    if (i < N) row_ptr[i] += blockoffs[blockIdx.x];
    if (i == 0) row_ptr[N] = E;
}

__global__ void scatter_k(const int* __restrict__ row, const int* __restrict__ col,
                          const float* __restrict__ dinv, int* __restrict__ cursor,
                          int* __restrict__ srcS, float* __restrict__ nrmS, int E) {
    int e = blockIdx.x * 256 + threadIdx.x;
    if (e < E) {
        int c = col[e], r = row[e];
        int pos = atomicAdd(&cursor[c], 1);
        srcS[pos] = r;
        nrmS[pos] = dinv[r] * dinv[c];
    }
}

// ---------- h0 = relu(x @ W_in + b_in), also copied into hA ----------
__global__ __launch_bounds__(128) void h0_k(const float* __restrict__ x,
                                            const float* __restrict__ Win,
                                            const float* __restrict__ bin,
                                            float* __restrict__ h0,
                                            float* __restrict__ h,
                                            int N) {
    __shared__ float xs[NB * 256];
    int t = threadIdx.x;
    int base = blockIdx.x * NB;
    for (int idx = t; idx < NB * 256; idx += 128) {
        int m = idx >> 8, k = idx & 255;
        int n = base + m;
        xs[idx] = (n < N) ? x[(size_t)n * 256 + k] : 0.f;
    }
    __syncthreads();
    int jq = t & 31, mg = t >> 5;
    float4 acc[8];
#pragma unroll
    for (int m = 0; m < 8; m++) acc[m] = make_float4(0.f, 0.f, 0.f, 0.f);
    const float4* W4 = (const float4*)Win;
    for (int k = 0; k < 256; k++) {
        float4 w = W4[k * 32 + jq];
#pragma unroll
        for (int m = 0; m < 8; m++) {
            float a = xs[(mg * 8 + m) * 256 + k];
            acc[m].x += a * w.x; acc[m].y += a * w.y;
            acc[m].z += a * w.z; acc[m].w += a * w.w;
        }
    }
    float4 b4 = ((const float4*)bin)[jq];
#pragma unroll
    for (int m = 0; m < 8; m++) {
        int n = base + mg * 8 + m;
        if (n < N) {
            float4 r;
            r.x = fmaxf(acc[m].x + b4.x, 0.f);
            r.y = fmaxf(acc[m].y + b4.y, 0.f);
            r.z = fmaxf(acc[m].z + b4.z, 0.f);
            r.w = fmaxf(acc[m].w + b4.w, 0.f);
            *(float4*)&h0[(size_t)n * HID + jq * 4] = r;
            *(float4*)&h[(size_t)n * HID + jq * 4] = r;
        }
    }
}

// ---------- fused layer: s = 0.9*Ahat@h + 0.1*h0 ; h_out = relu((1-b)s + b*(s@W)) ----------
__global__ __launch_bounds__(128) void layer_k(const float* __restrict__ h_in,
                                               float* __restrict__ h_out,
                                               const float* __restrict__ h0,
                                               const float* __restrict__ dinv,
                                               const int* __restrict__ row_ptr,
                                               const int* __restrict__ srcS,
                                               const float* __restrict__ nrmS,
                                               const float* __restrict__ W,
                                               float beta, int N) {
    __shared__ float s_lds[NB * HID];
    int t = threadIdx.x;
    int base = blockIdx.x * NB;

    // Phase A: SpMM rows for NB nodes; thread t = feature j
    for (int m = 0; m < NB; m++) {
        int dst = base + m;
        if (dst >= N) { s_lds[m * HID + t] = 0.f; continue; }  // block-uniform branch
        float dv = dinv[dst];
        float acc = h_in[(size_t)dst * HID + t] * (dv * dv);
        int beg = row_ptr[dst], end = row_ptr[dst + 1];
        for (int e = beg; e < end; e++) {
            int sn = srcS[e];
            float w = nrmS[e];
            acc += h_in[(size_t)sn * HID + t] * w;
        }
        s_lds[m * HID + t] = 0.9f * acc + 0.1f * h0[(size_t)dst * HID + t];
    }
    __syncthreads();

    // Phase B: y = s @ W (register-tiled: 8 nodes x 4 feats per thread)
    int jq = t & 31, mg = t >> 5;
    float4 acc[8];
#pragma unroll
    for (int m = 0; m < 8; m++) acc[m] = make_float4(0.f, 0.f, 0.f, 0.f);
    const float4* W4 = (const float4*)W;
    for (int k = 0; k < HID; k++) {
        float4 w = W4[k * 32 + jq];
#pragma unroll
        for (int m = 0; m < 8; m++) {
            float a = s_lds[(mg * 8 + m) * HID + k];  // 2 addrs per wave -> free 2-way
            acc[m].x += a * w.x; acc[m].y += a * w.y;
            acc[m].z += a * w.z; acc[m].w += a * w.w;
        }
    }
    float ob = 1.0f - beta;
#pragma unroll
    for (int m = 0; m < 8; m++) {
        int mm = mg * 8 + m;
        int dst = base + mm;
        if (dst < N) {
            float4 sv = *(const float4*)&s_lds[mm * HID + jq * 4];
            float4 r;
            r.x = fmaxf(ob * sv.x + beta * acc[m].x, 0.f);
            r.y = fmaxf(ob * sv.y + beta * acc[m].y, 0.f);
            r.z = fmaxf(ob * sv.z + beta * acc[m].z, 0.f);
            r.w = fmaxf(ob * sv.w + beta * acc[m].w, 0.f);
            *(float4*)&h_out[(size_t)dst * HID + jq * 4] = r;
        }
    }
}

// ---------- out = h @ W_out + b_out ----------
__global__ void out_k(const float* __restrict__ h, const float* __restrict__ Wout,
                      const float* __restrict__ bout, float* __restrict__ out, int N) {
    int t = threadIdx.x;
    int lane = t & 63;
    int wv = t >> 6;  // 4 waves/block, one node each
    int n = blockIdx.x * 4 + wv;
    if (n >= N) return;
    float v = h[(size_t)n * HID + lane] * Wout[lane]
            + h[(size_t)n * HID + 64 + lane] * Wout[64 + lane];
#pragma unroll
    for (int off = 32; off > 0; off >>= 1) v += __shfl_down(v, off, 64);
    if (lane == 0) out[n] = v + bout[0];
}

extern "C" void kernel_launch(void* const* d_in, const int* in_sizes, int n_in,
                              void* d_out, int out_size, void* d_ws, size_t ws_size,
                              hipStream_t stream) {
    const float* x    = (const float*)d_in[0];
    const int*   ei   = (const int*)d_in[1];
    const float* Win  = (const float*)d_in[2];
    const float* bin  = (const float*)d_in[3];
    const float* convs= (const float*)d_in[4];
    const float* Wout = (const float*)d_in[5];
    const float* bout = (const float*)d_in[6];

    int N = in_sizes[0] / 256;
    int E = in_sizes[1] / 2;
    const int* row = ei;       // sources
    const int* col = ei + E;   // destinations

    char* ws = (char*)d_ws;
    size_t off = 0;
    auto alloc = [&](size_t bytes) -> char* {
        char* p = ws + off;
        off = (off + bytes + 255) & ~(size_t)255;
        return p;
    };
    int*   counts    = (int*)alloc((size_t)N * 4);
    int*   row_ptr   = (int*)alloc((size_t)(N + 1) * 4);
    int*   cursor    = (int*)alloc((size_t)N * 4);
    int*   blocksums = (int*)alloc(512 * 4);
    int*   blockoffs = (int*)alloc(512 * 4);
    float* dinv      = (float*)alloc((size_t)N * 4);
    int*   srcS      = (int*)alloc((size_t)E * 4);
    float* nrmS      = (float*)alloc((size_t)E * 4);
    float* h0        = (float*)alloc((size_t)N * HID * 4);
    float* hA        = (float*)alloc((size_t)N * HID * 4);
    float* hB        = (float*)alloc((size_t)N * HID * 4);

    int eb = (E + 255) / 256;
    int nb = (N + 255) / 256;

    hipMemsetAsync(counts, 0, (size_t)N * 4, stream);
    degree_k<<<eb, 256, 0, stream>>>(col, counts, E);
    dinv_k<<<nb, 256, 0, stream>>>(counts, dinv, N);
    scan1_k<<<nb, 256, 0, stream>>>(counts, row_ptr, blocksums, N);
    scan2_k<<<1, 512, 0, stream>>>(blocksums, blockoffs, nb);
    scan3_k<<<nb, 256, 0, stream>>>(row_ptr, blockoffs, N, E);
    hipMemcpyAsync(cursor, row_ptr, (size_t)N * 4, hipMemcpyDeviceToDevice, stream);
    scatter_k<<<eb, 256, 0, stream>>>(row, col, dinv, cursor, srcS, nrmS, E);

    int gb = (N + NB - 1) / NB;
    h0_k<<<gb, 128, 0, stream>>>(x, Win, bin, h0, hA, N);

    float* hin = hA;
    float* hout = hB;
    for (int i = 0; i < 8; i++) {
        float beta = (float)log(0.5 / (double)(i + 1) + 1.0);
        layer_k<<<gb, 128, 0, stream>>>(hin, hout, h0, dinv, row_ptr, srcS, nrmS,
                                        convs + (size_t)i * HID * HID, beta, N);
        float* tp = hin; hin = hout; hout = tp;
    }
    out_k<<<(N + 3) / 4, 256, 0, stream>>>(hin, Wout, bout, (float*)d_out, N);
}

// Round 2
// 1737.494 us; speedup vs baseline: 2.1339x; 2.1339x over previous
//
#include <hip/hip_runtime.h>
#include <math.h>

#define HID 128
#define NB 32   // nodes per block in fused layer kernel

// ---------- CSR build ----------
__global__ void degree_k(const int* __restrict__ col, int* __restrict__ counts, int E) {
    int e = blockIdx.x * 256 + threadIdx.x;
    if (e < E) atomicAdd(&counts[col[e]], 1);
}

__global__ void dinv_k(const int* __restrict__ counts, float* __restrict__ dinv, int N) {
    int i = blockIdx.x * 256 + threadIdx.x;
    if (i < N) dinv[i] = rsqrtf((float)counts[i] + 1.0f);
}

__global__ void scan1_k(const int* __restrict__ counts, int* __restrict__ row_ptr,
                        int* __restrict__ blocksums, int N) {
    __shared__ int tmp[256];
    int t = threadIdx.x;
    int i = blockIdx.x * 256 + t;
    int v = (i < N) ? counts[i] : 0;
    tmp[t] = v;
    __syncthreads();
    for (int off = 1; off < 256; off <<= 1) {
        int x = (t >= off) ? tmp[t - off] : 0;
        __syncthreads();
        tmp[t] += x;
        __syncthreads();
    }
    if (i < N) row_ptr[i] = tmp[t] - v;          // exclusive within block
    if (t == 255) blocksums[blockIdx.x] = tmp[t]; // block total
}

__global__ void scan2_k(const int* __restrict__ blocksums, int* __restrict__ blockoffs, int nb) {
    __shared__ int tmp[512];
    int t = threadIdx.x;
    int v = (t < nb) ? blocksums[t] : 0;
    tmp[t] = v;
    __syncthreads();
    for (int off = 1; off < 512; off <<= 1) {
        int x = (t >= off) ? tmp[t - off] : 0;
        __syncthreads();
        tmp[t] += x;
        __syncthreads();
    }
    if (t < nb) blockoffs[t] = tmp[t] - v;        // exclusive
}

__global__ void scan3_k(int* __restrict__ row_ptr, const int* __restrict__ blockoffs, int N, int E) {
    int i = blockIdx.x * 256 + threadIdx.x;
    if (i < N) row_ptr[i] += blockoffs[blockIdx.x];
    if (i == 0) row_ptr[N] = E;
}

// edges[pos] = {src_node, bitcast(norm)} — one 8B record per edge
__global__ void scatter_k(const int* __restrict__ row, const int* __restrict__ col,
                          const float* __restrict__ dinv, int* __restrict__ cursor,
                          int2* __restrict__ edges, int E) {
    int e = blockIdx.x * 256 + threadIdx.x;
    if (e < E) {
        int c = col[e], r = row[e];
        int pos = atomicAdd(&cursor[c], 1);
        edges[pos] = make_int2(r, __float_as_int(dinv[r] * dinv[c]));
    }
}

// ---------- h0 = relu(x @ W_in + b_in), also copied into hA ----------
__global__ __launch_bounds__(256) void h0_k(const float* __restrict__ x,
                                            const float* __restrict__ Win,
                                            const float* __restrict__ bin,
                                            float* __restrict__ h0,
                                            float* __restrict__ h,
                                            int N) {
    __shared__ float xs[NB * 256];   // 32 KB
    int t = threadIdx.x;
    int base = blockIdx.x * NB;
    // stage x tile: 8192 floats = 2048 float4
    const float4* x4 = (const float4*)(x + (size_t)base * 256);
    float4* xs4 = (float4*)xs;
    for (int idx = t; idx < 2048; idx += 256) xs4[idx] = x4[idx];
    __syncthreads();

    int jq = t & 31, mg = t >> 5;     // 4 nodes x 4 feats per thread
    float4 acc[4];
#pragma unroll
    for (int m = 0; m < 4; m++) acc[m] = make_float4(0.f, 0.f, 0.f, 0.f);
    const float4* W4 = (const float4*)Win;
    for (int k = 0; k < 256; k++) {
        float4 w = W4[k * 32 + jq];
#pragma unroll
        for (int m = 0; m < 4; m++) {
            float a = xs[(mg * 4 + m) * 256 + k];   // broadcast per half-wave
            acc[m].x += a * w.x; acc[m].y += a * w.y;
            acc[m].z += a * w.z; acc[m].w += a * w.w;
        }
    }
    float4 b4 = ((const float4*)bin)[jq];
#pragma unroll
    for (int m = 0; m < 4; m++) {
        int n = base + mg * 4 + m;
        if (n < N) {
            float4 r;
            r.x = fmaxf(acc[m].x + b4.x, 0.f);
            r.y = fmaxf(acc[m].y + b4.y, 0.f);
            r.z = fmaxf(acc[m].z + b4.z, 0.f);
            r.w = fmaxf(acc[m].w + b4.w, 0.f);
            *(float4*)&h0[(size_t)n * HID + jq * 4] = r;
            *(float4*)&h[(size_t)n * HID + jq * 4] = r;
        }
    }
}

// ---------- fused layer: s = 0.9*Ahat@h + 0.1*h0 ; h_out = relu((1-b)s + b*(s@W)) ----------
// Phase A: one wave per node (4 nodes in flight), lane = float2 of features.
// Edge records for a node are loaded 64-at-a-time coalesced, broadcast via shfl.
__global__ __launch_bounds__(256) void layer_k(const float* __restrict__ h_in,
                                               float* __restrict__ h_out,
                                               const float* __restrict__ h0,
                                               const float* __restrict__ dinv,
                                               const int* __restrict__ row_ptr,
                                               const int2* __restrict__ edges,
                                               const float* __restrict__ W,
                                               float beta, int N) {
    __shared__ float s_lds[NB * HID];   // 16 KB
    int t = threadIdx.x;
    int lane = t & 63;
    int wv = t >> 6;                    // wave 0..3
    int base = blockIdx.x * NB;

    for (int m = wv; m < NB; m += 4) {
        int dst = base + m;
        if (dst >= N) {
            s_lds[m * HID + lane * 2] = 0.f;
            s_lds[m * HID + lane * 2 + 1] = 0.f;
            continue;
        }
        float dv = dinv[dst];
        float2 hv = *(const float2*)&h_in[(size_t)dst * HID + lane * 2];
        float ax = hv.x * (dv * dv), ay = hv.y * (dv * dv);
        int beg = row_ptr[dst], end = row_ptr[dst + 1];
        for (int b = beg; b < end; b += 64) {
            int cnt = min(64, end - b);
            int2 ed = make_int2(0, 0);
            if (lane < cnt) ed = edges[b + lane];   // one coalesced 512B load
            int i = 0;
            for (; i + 4 <= cnt; i += 4) {
                int s0 = __shfl(ed.x, i, 64);     float w0 = __int_as_float(__shfl(ed.y, i, 64));
                int s1 = __shfl(ed.x, i + 1, 64); float w1 = __int_as_float(__shfl(ed.y, i + 1, 64));
                int s2 = __shfl(ed.x, i + 2, 64); float w2 = __int_as_float(__shfl(ed.y, i + 2, 64));
                int s3 = __shfl(ed.x, i + 3, 64); float w3 = __int_as_float(__shfl(ed.y, i + 3, 64));
                float2 g0 = *(const float2*)&h_in[(size_t)s0 * HID + lane * 2];
                float2 g1 = *(const float2*)&h_in[(size_t)s1 * HID + lane * 2];
                float2 g2 = *(const float2*)&h_in[(size_t)s2 * HID + lane * 2];
                float2 g3 = *(const float2*)&h_in[(size_t)s3 * HID + lane * 2];
                ax += g0.x * w0; ay += g0.y * w0;
                ax += g1.x * w1; ay += g1.y * w1;
                ax += g2.x * w2; ay += g2.y * w2;
                ax += g3.x * w3; ay += g3.y * w3;
            }
            for (; i < cnt; i++) {
                int sn = __shfl(ed.x, i, 64);
                float w = __int_as_float(__shfl(ed.y, i, 64));
                float2 g = *(const float2*)&h_in[(size_t)sn * HID + lane * 2];
                ax += g.x * w; ay += g.y * w;
            }
        }
        float2 h0v = *(const float2*)&h0[(size_t)dst * HID + lane * 2];
        s_lds[m * HID + lane * 2]     = 0.9f * ax + 0.1f * h0v.x;
        s_lds[m * HID + lane * 2 + 1] = 0.9f * ay + 0.1f * h0v.y;
    }
    __syncthreads();

    // Phase B: y = s @ W (register-tiled: 4 nodes x 4 feats per thread)
    int jq = t & 31, mg = t >> 5;
    float4 acc[4];
#pragma unroll
    for (int m = 0; m < 4; m++) acc[m] = make_float4(0.f, 0.f, 0.f, 0.f);
    const float4* W4 = (const float4*)W;
    for (int k = 0; k < HID; k++) {
        float4 w = W4[k * 32 + jq];
#pragma unroll
        for (int m = 0; m < 4; m++) {
            float a = s_lds[(mg * 4 + m) * HID + k];   // broadcast per half-wave
            acc[m].x += a * w.x; acc[m].y += a * w.y;
            acc[m].z += a * w.z; acc[m].w += a * w.w;
        }
    }
    float ob = 1.0f - beta;
#pragma unroll
    for (int m = 0; m < 4; m++) {
        int mm = mg * 4 + m;
        int dst = base + mm;
        if (dst < N) {
            float4 sv = *(const float4*)&s_lds[mm * HID + jq * 4];
            float4 r;
            r.x = fmaxf(ob * sv.x + beta * acc[m].x, 0.f);
            r.y = fmaxf(ob * sv.y + beta * acc[m].y, 0.f);
            r.z = fmaxf(ob * sv.z + beta * acc[m].z, 0.f);
            r.w = fmaxf(ob * sv.w + beta * acc[m].w, 0.f);
            *(float4*)&h_out[(size_t)dst * HID + jq * 4] = r;
        }
    }
}

// ---------- out = h @ W_out + b_out ----------
__global__ void out_k(const float* __restrict__ h, const float* __restrict__ Wout,
                      const float* __restrict__ bout, float* __restrict__ out, int N) {
    int t = threadIdx.x;
    int lane = t & 63;
    int wv = t >> 6;  // 4 waves/block, one node each
    int n = blockIdx.x * 4 + wv;
    if (n >= N) return;
    float v = h[(size_t)n * HID + lane] * Wout[lane]
            + h[(size_t)n * HID + 64 + lane] * Wout[64 + lane];
#pragma unroll
    for (int off = 32; off > 0; off >>= 1) v += __shfl_down(v, off, 64);
    if (lane == 0) out[n] = v + bout[0];
}

extern "C" void kernel_launch(void* const* d_in, const int* in_sizes, int n_in,
                              void* d_out, int out_size, void* d_ws, size_t ws_size,
                              hipStream_t stream) {
    const float* x    = (const float*)d_in[0];
    const int*   ei   = (const int*)d_in[1];
    const float* Win  = (const float*)d_in[2];
    const float* bin  = (const float*)d_in[3];
    const float* convs= (const float*)d_in[4];
    const float* Wout = (const float*)d_in[5];
    const float* bout = (const float*)d_in[6];

    int N = in_sizes[0] / 256;
    int E = in_sizes[1] / 2;
    const int* row = ei;       // sources
    const int* col = ei + E;   // destinations

    char* ws = (char*)d_ws;
    size_t off = 0;
    auto alloc = [&](size_t bytes) -> char* {
        char* p = ws + off;
        off = (off + bytes + 255) & ~(size_t)255;
        return p;
    };
    int*   counts    = (int*)alloc((size_t)N * 4);
    int*   row_ptr   = (int*)alloc((size_t)(N + 1) * 4);
    int*   cursor    = (int*)alloc((size_t)N * 4);
    int*   blocksums = (int*)alloc(512 * 4);
    int*   blockoffs = (int*)alloc(512 * 4);
    float* dinv      = (float*)alloc((size_t)N * 4);
    int2*  edges     = (int2*)alloc((size_t)E * 8);
    float* h0        = (float*)alloc((size_t)N * HID * 4);
    float* hA        = (float*)alloc((size_t)N * HID * 4);
    float* hB        = (float*)alloc((size_t)N * HID * 4);

    int eb = (E + 255) / 256;
    int nb = (N + 255) / 256;

    hipMemsetAsync(counts, 0, (size_t)N * 4, stream);
    degree_k<<<eb, 256, 0, stream>>>(col, counts, E);
    dinv_k<<<nb, 256, 0, stream>>>(counts, dinv, N);
    scan1_k<<<nb, 256, 0, stream>>>(counts, row_ptr, blocksums, N);
    scan2_k<<<1, 512, 0, stream>>>(blocksums, blockoffs, nb);
    scan3_k<<<nb, 256, 0, stream>>>(row_ptr, blockoffs, N, E);
    hipMemcpyAsync(cursor, row_ptr, (size_t)N * 4, hipMemcpyDeviceToDevice, stream);
    scatter_k<<<eb, 256, 0, stream>>>(row, col, dinv, cursor, edges, E);

    int gb = (N + NB - 1) / NB;
    h0_k<<<gb, 256, 0, stream>>>(x, Win, bin, h0, hA, N);

    float* hin = hA;
    float* hout = hB;
    for (int i = 0; i < 8; i++) {
        float beta = (float)log(0.5 / (double)(i + 1) + 1.0);
        layer_k<<<gb, 256, 0, stream>>>(hin, hout, h0, dinv, row_ptr, edges,
                                        convs + (size_t)i * HID * HID, beta, N);
        float* tp = hin; hin = hout; hout = tp;
    }
    out_k<<<(N + 3) / 4, 256, 0, stream>>>(hin, Wout, bout, (float*)d_out, N);
}

// Round 3
// 1321.948 us; speedup vs baseline: 2.8046x; 1.3143x over previous
//
#include <hip/hip_runtime.h>
#include <math.h>

#define HID 128
#define NB 32   // nodes per block in fused layer kernel

typedef unsigned int uint32;
typedef unsigned short ushort16;

__device__ __forceinline__ unsigned short f2bf(float f) {
    unsigned u = __float_as_uint(f);
    u += 0x7FFF + ((u >> 16) & 1);          // round-to-nearest-even
    return (unsigned short)(u >> 16);
}
__device__ __forceinline__ float bf_lo(uint32 u) { return __uint_as_float(u << 16); }
__device__ __forceinline__ float bf_hi(uint32 u) { return __uint_as_float(u & 0xFFFF0000u); }

// ---------- CSR build ----------
__global__ void degree_k(const int* __restrict__ col, int* __restrict__ counts, int E) {
    int e = blockIdx.x * 256 + threadIdx.x;
    if (e < E) atomicAdd(&counts[col[e]], 1);
}

__global__ void dinv_k(const int* __restrict__ counts, float* __restrict__ dinv, int N) {
    int i = blockIdx.x * 256 + threadIdx.x;
    if (i < N) dinv[i] = rsqrtf((float)counts[i] + 1.0f);
}

__global__ void scan1_k(const int* __restrict__ counts, int* __restrict__ row_ptr,
                        int* __restrict__ blocksums, int N) {
    __shared__ int tmp[256];
    int t = threadIdx.x;
    int i = blockIdx.x * 256 + t;
    int v = (i < N) ? counts[i] : 0;
    tmp[t] = v;
    __syncthreads();
    for (int off = 1; off < 256; off <<= 1) {
        int x = (t >= off) ? tmp[t - off] : 0;
        __syncthreads();
        tmp[t] += x;
        __syncthreads();
    }
    if (i < N) row_ptr[i] = tmp[t] - v;
    if (t == 255) blocksums[blockIdx.x] = tmp[t];
}

__global__ void scan2_k(const int* __restrict__ blocksums, int* __restrict__ blockoffs, int nb) {
    __shared__ int tmp[512];
    int t = threadIdx.x;
    int v = (t < nb) ? blocksums[t] : 0;
    tmp[t] = v;
    __syncthreads();
    for (int off = 1; off < 512; off <<= 1) {
        int x = (t >= off) ? tmp[t - off] : 0;
        __syncthreads();
        tmp[t] += x;
        __syncthreads();
    }
    if (t < nb) blockoffs[t] = tmp[t] - v;
}

__global__ void scan3_k(int* __restrict__ row_ptr, const int* __restrict__ blockoffs, int N, int E) {
    int i = blockIdx.x * 256 + threadIdx.x;
    if (i < N) row_ptr[i] += blockoffs[blockIdx.x];
    if (i == 0) row_ptr[N] = E;
}

// edges[pos] = {src_node, bitcast(norm)} — one 8B record per edge
__global__ void scatter_k(const int* __restrict__ row, const int* __restrict__ col,
                          const float* __restrict__ dinv, int* __restrict__ cursor,
                          int2* __restrict__ edges, int E) {
    int e = blockIdx.x * 256 + threadIdx.x;
    if (e < E) {
        int c = col[e], r = row[e];
        int pos = atomicAdd(&cursor[c], 1);
        edges[pos] = make_int2(r, __float_as_int(dinv[r] * dinv[c]));
    }
}

// ---------- h0 = relu(x @ W_in + b_in) (fp32), h = bf16(h0) ----------
__global__ __launch_bounds__(256) void h0_k(const float* __restrict__ x,
                                            const float* __restrict__ Win,
                                            const float* __restrict__ bin,
                                            float* __restrict__ h0,
                                            ushort16* __restrict__ h,
                                            int N) {
    __shared__ float xs[NB * 256];   // 32 KB
    int t = threadIdx.x;
    int base = blockIdx.x * NB;
    const float4* x4 = (const float4*)(x + (size_t)base * 256);
    float4* xs4 = (float4*)xs;
    for (int idx = t; idx < 2048; idx += 256) xs4[idx] = x4[idx];
    __syncthreads();

    int jq = t & 31, mg = t >> 5;     // 4 nodes x 4 feats per thread
    float4 acc[4];
#pragma unroll
    for (int m = 0; m < 4; m++) acc[m] = make_float4(0.f, 0.f, 0.f, 0.f);
    const float4* W4 = (const float4*)Win;
    for (int k = 0; k < 256; k += 4) {          // unroll 4: 4 W loads in flight
        float4 w0 = W4[(k + 0) * 32 + jq];
        float4 w1 = W4[(k + 1) * 32 + jq];
        float4 w2 = W4[(k + 2) * 32 + jq];
        float4 w3 = W4[(k + 3) * 32 + jq];
#pragma unroll
        for (int m = 0; m < 4; m++) {
            const float* xr = &xs[(mg * 4 + m) * 256 + k];
            float a0 = xr[0], a1 = xr[1], a2 = xr[2], a3 = xr[3];
            acc[m].x += a0 * w0.x; acc[m].y += a0 * w0.y; acc[m].z += a0 * w0.z; acc[m].w += a0 * w0.w;
            acc[m].x += a1 * w1.x; acc[m].y += a1 * w1.y; acc[m].z += a1 * w1.z; acc[m].w += a1 * w1.w;
            acc[m].x += a2 * w2.x; acc[m].y += a2 * w2.y; acc[m].z += a2 * w2.z; acc[m].w += a2 * w2.w;
            acc[m].x += a3 * w3.x; acc[m].y += a3 * w3.y; acc[m].z += a3 * w3.z; acc[m].w += a3 * w3.w;
        }
    }
    float4 b4 = ((const float4*)bin)[jq];
#pragma unroll
    for (int m = 0; m < 4; m++) {
        int n = base + mg * 4 + m;
        if (n < N) {
            float4 r;
            r.x = fmaxf(acc[m].x + b4.x, 0.f);
            r.y = fmaxf(acc[m].y + b4.y, 0.f);
            r.z = fmaxf(acc[m].z + b4.z, 0.f);
            r.w = fmaxf(acc[m].w + b4.w, 0.f);
            *(float4*)&h0[(size_t)n * HID + jq * 4] = r;
            ushort4 hb;
            hb.x = f2bf(r.x); hb.y = f2bf(r.y); hb.z = f2bf(r.z); hb.w = f2bf(r.w);
            *(ushort4*)&h[(size_t)n * HID + jq * 4] = hb;
        }
    }
}

// ---------- fused layer: s = 0.9*Ahat@h + 0.1*h0 ; h_out = relu((1-b)s + b*(s@W)) ----------
// h stored bf16 (gather bytes halved); all accumulation fp32.
__global__ __launch_bounds__(256) void layer_k(const ushort16* __restrict__ h_in,
                                               ushort16* __restrict__ h_out,
                                               const float* __restrict__ h0,
                                               const float* __restrict__ dinv,
                                               const int* __restrict__ row_ptr,
                                               const int2* __restrict__ edges,
                                               const float* __restrict__ W,
                                               float beta, int N) {
    __shared__ float s_lds[NB * HID];   // 16 KB
    int t = threadIdx.x;
    int lane = t & 63;
    int wv = t >> 6;
    int base = blockIdx.x * NB;

    for (int m = wv; m < NB; m += 4) {
        int dst = base + m;
        if (dst >= N) {
            s_lds[m * HID + lane * 2] = 0.f;
            s_lds[m * HID + lane * 2 + 1] = 0.f;
            continue;
        }
        float dv = dinv[dst];
        float dv2 = dv * dv;
        uint32 hu = *(const uint32*)&h_in[(size_t)dst * HID + lane * 2];
        float ax = bf_lo(hu) * dv2, ay = bf_hi(hu) * dv2;
        int beg = row_ptr[dst], end = row_ptr[dst + 1];
        for (int b = beg; b < end; b += 64) {
            int cnt = min(64, end - b);
            int2 ed = make_int2(0, 0);
            if (lane < cnt) ed = edges[b + lane];   // one coalesced 512B load
            int i = 0;
            for (; i + 4 <= cnt; i += 4) {
                int s0 = __shfl(ed.x, i, 64);     float w0 = __int_as_float(__shfl(ed.y, i, 64));
                int s1 = __shfl(ed.x, i + 1, 64); float w1 = __int_as_float(__shfl(ed.y, i + 1, 64));
                int s2 = __shfl(ed.x, i + 2, 64); float w2 = __int_as_float(__shfl(ed.y, i + 2, 64));
                int s3 = __shfl(ed.x, i + 3, 64); float w3 = __int_as_float(__shfl(ed.y, i + 3, 64));
                uint32 g0 = *(const uint32*)&h_in[(size_t)s0 * HID + lane * 2];
                uint32 g1 = *(const uint32*)&h_in[(size_t)s1 * HID + lane * 2];
                uint32 g2 = *(const uint32*)&h_in[(size_t)s2 * HID + lane * 2];
                uint32 g3 = *(const uint32*)&h_in[(size_t)s3 * HID + lane * 2];
                ax += bf_lo(g0) * w0; ay += bf_hi(g0) * w0;
                ax += bf_lo(g1) * w1; ay += bf_hi(g1) * w1;
                ax += bf_lo(g2) * w2; ay += bf_hi(g2) * w2;
                ax += bf_lo(g3) * w3; ay += bf_hi(g3) * w3;
            }
            for (; i < cnt; i++) {
                int sn = __shfl(ed.x, i, 64);
                float w = __int_as_float(__shfl(ed.y, i, 64));
                uint32 g = *(const uint32*)&h_in[(size_t)sn * HID + lane * 2];
                ax += bf_lo(g) * w; ay += bf_hi(g) * w;
            }
        }
        float2 h0v = *(const float2*)&h0[(size_t)dst * HID + lane * 2];
        s_lds[m * HID + lane * 2]     = 0.9f * ax + 0.1f * h0v.x;
        s_lds[m * HID + lane * 2 + 1] = 0.9f * ay + 0.1f * h0v.y;
    }
    __syncthreads();

    // Phase B: y = s @ W (fp32, register-tiled: 4 nodes x 4 feats per thread)
    int jq = t & 31, mg = t >> 5;
    float4 acc[4];
#pragma unroll
    for (int m = 0; m < 4; m++) acc[m] = make_float4(0.f, 0.f, 0.f, 0.f);
    const float4* W4 = (const float4*)W;
    for (int k = 0; k < HID; k += 2) {
        float4 w0 = W4[k * 32 + jq];
        float4 w1 = W4[(k + 1) * 32 + jq];
#pragma unroll
        for (int m = 0; m < 4; m++) {
            float a0 = s_lds[(mg * 4 + m) * HID + k];
            float a1 = s_lds[(mg * 4 + m) * HID + k + 1];
            acc[m].x += a0 * w0.x; acc[m].y += a0 * w0.y; acc[m].z += a0 * w0.z; acc[m].w += a0 * w0.w;
            acc[m].x += a1 * w1.x; acc[m].y += a1 * w1.y; acc[m].z += a1 * w1.z; acc[m].w += a1 * w1.w;
        }
    }
    float ob = 1.0f - beta;
#pragma unroll
    for (int m = 0; m < 4; m++) {
        int mm = mg * 4 + m;
        int dst = base + mm;
        if (dst < N) {
            float4 sv = *(const float4*)&s_lds[mm * HID + jq * 4];
            ushort4 hb;
            hb.x = f2bf(fmaxf(ob * sv.x + beta * acc[m].x, 0.f));
            hb.y = f2bf(fmaxf(ob * sv.y + beta * acc[m].y, 0.f));
            hb.z = f2bf(fmaxf(ob * sv.z + beta * acc[m].z, 0.f));
            hb.w = f2bf(fmaxf(ob * sv.w + beta * acc[m].w, 0.f));
            *(ushort4*)&h_out[(size_t)dst * HID + jq * 4] = hb;
        }
    }
}

// ---------- out = h @ W_out + b_out ----------
__global__ void out_k(const ushort16* __restrict__ h, const float* __restrict__ Wout,
                      const float* __restrict__ bout, float* __restrict__ out, int N) {
    int t = threadIdx.x;
    int lane = t & 63;
    int wv = t >> 6;  // 4 waves/block, one node each
    int n = blockIdx.x * 4 + wv;
    if (n >= N) return;
    uint32 u = *(const uint32*)&h[(size_t)n * HID + lane * 2];
    float v = bf_lo(u) * Wout[lane * 2] + bf_hi(u) * Wout[lane * 2 + 1];
#pragma unroll
    for (int off = 32; off > 0; off >>= 1) v += __shfl_down(v, off, 64);
    if (lane == 0) out[n] = v + bout[0];
}

extern "C" void kernel_launch(void* const* d_in, const int* in_sizes, int n_in,
                              void* d_out, int out_size, void* d_ws, size_t ws_size,
                              hipStream_t stream) {
    const float* x    = (const float*)d_in[0];
    const int*   ei   = (const int*)d_in[1];
    const float* Win  = (const float*)d_in[2];
    const float* bin  = (const float*)d_in[3];
    const float* convs= (const float*)d_in[4];
    const float* Wout = (const float*)d_in[5];
    const float* bout = (const float*)d_in[6];

    int N = in_sizes[0] / 256;
    int E = in_sizes[1] / 2;
    const int* row = ei;       // sources
    const int* col = ei + E;   // destinations

    char* ws = (char*)d_ws;
    size_t off = 0;
    auto alloc = [&](size_t bytes) -> char* {
        char* p = ws + off;
        off = (off + bytes + 255) & ~(size_t)255;
        return p;
    };
    int*      counts    = (int*)alloc((size_t)N * 4);
    int*      row_ptr   = (int*)alloc((size_t)(N + 1) * 4);
    int*      cursor    = (int*)alloc((size_t)N * 4);
    int*      blocksums = (int*)alloc(512 * 4);
    int*      blockoffs = (int*)alloc(512 * 4);
    float*    dinv      = (float*)alloc((size_t)N * 4);
    int2*     edges     = (int2*)alloc((size_t)E * 8);
    float*    h0        = (float*)alloc((size_t)N * HID * 4);
    ushort16* hA        = (ushort16*)alloc((size_t)N * HID * 2);
    ushort16* hB        = (ushort16*)alloc((size_t)N * HID * 2);

    int eb = (E + 255) / 256;
    int nb = (N + 255) / 256;

    hipMemsetAsync(counts, 0, (size_t)N * 4, stream);
    degree_k<<<eb, 256, 0, stream>>>(col, counts, E);
    dinv_k<<<nb, 256, 0, stream>>>(counts, dinv, N);
    scan1_k<<<nb, 256, 0, stream>>>(counts, row_ptr, blocksums, N);
    scan2_k<<<1, 512, 0, stream>>>(blocksums, blockoffs, nb);
    scan3_k<<<nb, 256, 0, stream>>>(row_ptr, blockoffs, N, E);
    hipMemcpyAsync(cursor, row_ptr, (size_t)N * 4, hipMemcpyDeviceToDevice, stream);
    scatter_k<<<eb, 256, 0, stream>>>(row, col, dinv, cursor, edges, E);

    int gb = (N + NB - 1) / NB;
    h0_k<<<gb, 256, 0, stream>>>(x, Win, bin, h0, hA, N);

    ushort16* hin = hA;
    ushort16* hout = hB;
    for (int i = 0; i < 8; i++) {
        float beta = (float)log(0.5 / (double)(i + 1) + 1.0);
        layer_k<<<gb, 256, 0, stream>>>(hin, hout, h0, dinv, row_ptr, edges,
                                        convs + (size_t)i * HID * HID, beta, N);
        ushort16* tp = hin; hin = hout; hout = tp;
    }
    out_k<<<(N + 3) / 4, 256, 0, stream>>>(hin, Wout, bout, (float*)d_out, N);
}